// Round 6
// baseline (383.896 us; speedup 1.0000x reference)
//
#include <hip/hip_runtime.h>
#include <hip/hip_bf16.h>

typedef _Float16 f16x8 __attribute__((ext_vector_type(8)));
typedef _Float16 f16x2 __attribute__((ext_vector_type(2)));
typedef float    f32x4 __attribute__((ext_vector_type(4)));

#define LOG2E  1.44269504f
#define LOG2E2 2.88539008f

// Fused LSTM cell, merged rcp: A=1+2^(-f·log2e), B=1+2^(-i·log2e), C=1+2^(2g·log2e)
//   c' = (c·B·C + A·(C-2)) · rcp(A·B·C);  h = (E-2)·rcp(D·E)
// 5 exp2 + 2 rcp per cell. Gates bounded -> max exp ~2^52, safe in fp32.
__device__ __forceinline__ float cell3(float i_, float f_, float g_, float o_, float& c) {
    float A  = 1.0f + __builtin_amdgcn_exp2f(-LOG2E * f_);
    float Bv = 1.0f + __builtin_amdgcn_exp2f(-LOG2E * i_);
    float Cv = 1.0f + __builtin_amdgcn_exp2f(LOG2E2 * g_);
    float BC = Bv * Cv;
    float cn = fmaf(c, BC, A * (Cv - 2.0f)) * __builtin_amdgcn_rcpf(A * BC);
    c = cn;
    float D  = 1.0f + __builtin_amdgcn_exp2f(-LOG2E * o_);
    float E  = 1.0f + __builtin_amdgcn_exp2f(LOG2E2 * cn);
    return (E - 2.0f) * __builtin_amdgcn_rcpf(D * E);
}

__device__ __forceinline__ f16x8 bfrag8(const float* __restrict__ p) {
    const float4 w0 = *(const float4*)p;
    const float4 w1 = *(const float4*)(p + 4);
    f16x8 v;
    v[0] = (_Float16)w0.x; v[1] = (_Float16)w0.y; v[2] = (_Float16)w0.z; v[3] = (_Float16)w0.w;
    v[4] = (_Float16)w1.x; v[5] = (_Float16)w1.y; v[6] = (_Float16)w1.z; v[7] = (_Float16)w1.w;
    return v;
}

// ---------------------------------------------------------------------------
// K1: layer-0 scans. 1 wave = 2 tiles = 32 samples (weights shared; 16
// independent activation chains per lane feed the quarter-rate trans pipe).
// grid = (NT/8, 4[model*2+dir]).
// hist layout: hist[(m*NT+tile)*15*1024 + t*1024 + dir*512 + lane*8], f16x8.
// ---------------------------------------------------------------------------
__global__ __launch_bounds__(256, 2) void k1_l0(
    const float* __restrict__ pos,            // [32768,30,4]
    const float* __restrict__ lvl_Wih0, const float* __restrict__ lvl_Whh0,
    const float* __restrict__ lvl_b0,
    const float* __restrict__ vor_Wih0, const float* __restrict__ vor_Whh0,
    const float* __restrict__ vor_b0,
    _Float16* __restrict__ hist, int chunk_base, int NT)
{
    const int lane  = threadIdx.x & 63;
    const int wv    = threadIdx.x >> 6;
    const int n0    = lane & 15;
    const int quad  = lane >> 4;
    const int tpair = (blockIdx.x * 4 + wv) * 2;   // first tile of this wave's pair
    const int m     = blockIdx.y >> 1;
    const int dir   = blockIdx.y & 1;

    const float* Wih = (m ? vor_Wih0 : lvl_Wih0) + dir * 128 * 4;   // [128][4]
    const float* Whh = (m ? vor_Whh0 : lvl_Whh0) + dir * 128 * 32;  // [128][32]
    const float* bs  = (m ? vor_b0   : lvl_b0)   + dir * 128;       // [128]

    f16x8 WhhB[8], WihB[8];
#pragma unroll
    for (int nb = 0; nb < 8; ++nb) {
        const int row = (nb >> 1) * 32 + 2 * n0 + (nb & 1);   // permuted column
        WhhB[nb] = bfrag8(Whh + row * 32 + quad * 8);
        f16x8 v;
#pragma unroll
        for (int r = 0; r < 8; ++r) v[r] = (_Float16)0.0f;
        if (quad == 0) {                                      // k<4: Wih, k==4: bias
            const float4 w = *(const float4*)(Wih + row * 4);
            v[0] = (_Float16)w.x; v[1] = (_Float16)w.y;
            v[2] = (_Float16)w.z; v[3] = (_Float16)w.w;
            v[4] = (_Float16)bs[row];
        }
        WihB[nb] = v;
    }

    __shared__ _Float16 tb[4][2][640];            // 2 tiles x (16 rows x 40 f16) / wave
    _Float16* T0 = tb[wv][0];
    _Float16* T1 = tb[wv][1];

    const float* xp[2];
    _Float16*    hp[2];
#pragma unroll
    for (int tt = 0; tt < 2; ++tt) {
        const int s    = chunk_base + (tpair + tt) * 16 + n0;
        const int b    = s & 32767;
        const int hf   = s >> 15;
        xp[tt] = pos + ((size_t)b * 30 + hf * 15 + (dir ? 14 : 0)) * 4;
        hp[tt] = hist + ((size_t)(m * NT + tpair + tt)) * 15 * 1024
               + (size_t)(dir ? 14 : 0) * 1024 + dir * 512 + lane * 8;
    }
    const int xstep = dir ? -4 : 4;
    const int hstep = dir ? -1024 : 1024;

    float c[2][4][2];
#pragma unroll
    for (int tt = 0; tt < 2; ++tt)
#pragma unroll
        for (int r = 0; r < 4; ++r) { c[tt][r][0] = 0.0f; c[tt][r][1] = 0.0f; }
    f16x8 hfrag[2], xfrag[2];
#pragma unroll
    for (int tt = 0; tt < 2; ++tt) {
#pragma unroll
        for (int r = 0; r < 8; ++r) { hfrag[tt][r] = (_Float16)0.0f; xfrag[tt][r] = (_Float16)0.0f; }
        xfrag[tt][4] = (_Float16)1.0f;            // bias slot (k=4)
    }

    const f32x4 z4 = {0.0f, 0.0f, 0.0f, 0.0f};

#pragma unroll 1
    for (int ti = 0; ti < 15; ++ti) {
#pragma unroll
        for (int tt = 0; tt < 2; ++tt) {
            const float4 xv = *(const float4*)xp[tt];
            xp[tt] += xstep;
            xfrag[tt][0] = (_Float16)xv.x; xfrag[tt][1] = (_Float16)xv.y;
            xfrag[tt][2] = (_Float16)xv.z; xfrag[tt][3] = (_Float16)xv.w;
        }

        f32x4 acc[2][8];
#pragma unroll
        for (int tt = 0; tt < 2; ++tt)
#pragma unroll
            for (int nb = 0; nb < 8; ++nb)
                acc[tt][nb] = __builtin_amdgcn_mfma_f32_16x16x32_f16(xfrag[tt], WihB[nb], z4, 0, 0, 0);
#pragma unroll
        for (int tt = 0; tt < 2; ++tt)
#pragma unroll
            for (int nb = 0; nb < 8; ++nb)
                acc[tt][nb] = __builtin_amdgcn_mfma_f32_16x16x32_f16(hfrag[tt], WhhB[nb], acc[tt][nb], 0, 0, 0);

        // 16 independent cell chains per lane
#pragma unroll
        for (int tt = 0; tt < 2; ++tt) {
            _Float16* T = tt ? T1 : T0;
#pragma unroll
            for (int r = 0; r < 4; ++r) {
                f16x2 pk;
#pragma unroll
                for (int p = 0; p < 2; ++p) {
                    float h = cell3(acc[tt][0 + p][r], acc[tt][2 + p][r],
                                    acc[tt][4 + p][r], acc[tt][6 + p][r], c[tt][r][p]);
                    pk[p] = (_Float16)h;
                }
                *(f16x2*)(T + (quad * 4 + r) * 40 + 2 * n0) = pk;
            }
        }
#pragma unroll
        for (int tt = 0; tt < 2; ++tt) {
            hfrag[tt] = *(const f16x8*)((tt ? T1 : T0) + n0 * 40 + quad * 8);
            *(f16x8*)hp[tt] = hfrag[tt];
            hp[tt] += hstep;
        }
    }
}

// ---------------------------------------------------------------------------
// K2: layer-1 fwd scan + 1-step bwd + FC/mask epilogue. 1 wave = 2 tiles.
// grid = (NT/8, 2[model]).
// ---------------------------------------------------------------------------
__global__ __launch_bounds__(256, 1) void k2_l1(
    const float* __restrict__ dir_input,      // [32768,6]
    const float* __restrict__ lvl_Wih1, const float* __restrict__ lvl_Whh1,
    const float* __restrict__ lvl_b1,
    const float* __restrict__ vor_Wih1, const float* __restrict__ vor_Whh1,
    const float* __restrict__ vor_b1,
    const float* __restrict__ lvl_fc_W, const float* __restrict__ lvl_fc_b,
    const float* __restrict__ vor_fc_W, const float* __restrict__ vor_fc_b,
    const _Float16* __restrict__ hist, float* __restrict__ out,
    int chunk_base, int NT)
{
    const int lane  = threadIdx.x & 63;
    const int wv    = threadIdx.x >> 6;
    const int n0    = lane & 15;
    const int quad  = lane >> 4;
    const int tpair = (blockIdx.x * 4 + wv) * 2;
    const int m     = blockIdx.y;

    const float* Wih = m ? vor_Wih1 : lvl_Wih1;   // [2][128][64]
    const float* Whh = m ? vor_Whh1 : lvl_Whh1;   // [2][128][32]
    const float* bs  = m ? vor_b1   : lvl_b1;     // [2][128]

    f16x8 WA[8], WB[8], WH[8];
    float bias8[8];
#pragma unroll
    for (int nb = 0; nb < 8; ++nb) {
        const int row = (nb >> 1) * 32 + 2 * n0 + (nb & 1);
        WA[nb] = bfrag8(Wih + row * 64 + quad * 8);
        WB[nb] = bfrag8(Wih + row * 64 + 32 + quad * 8);
        WH[nb] = bfrag8(Whh + row * 32 + quad * 8);
        bias8[nb] = bs[row];
    }

    __shared__ _Float16 tb[4][2][640];
    _Float16* T0 = tb[wv][0];
    _Float16* T1 = tb[wv][1];

    const _Float16* hb[2];
#pragma unroll
    for (int tt = 0; tt < 2; ++tt)
        hb[tt] = hist + ((size_t)(m * NT + tpair + tt)) * 15 * 1024 + lane * 8;

    float c1[2][4][2];
#pragma unroll
    for (int tt = 0; tt < 2; ++tt)
#pragma unroll
        for (int r = 0; r < 4; ++r) { c1[tt][r][0] = 0.0f; c1[tt][r][1] = 0.0f; }
    f16x8 h1frag[2];
#pragma unroll
    for (int tt = 0; tt < 2; ++tt)
#pragma unroll
        for (int r = 0; r < 8; ++r) h1frag[tt][r] = (_Float16)0.0f;
    float h1f[2][4][2];
    f16x8 a_f[2], a_b[2];

#pragma unroll 1
    for (int t = 0; t < 15; ++t) {
#pragma unroll
        for (int tt = 0; tt < 2; ++tt) {
            a_f[tt] = *(const f16x8*)hb[tt];
            a_b[tt] = *(const f16x8*)(hb[tt] + 512);
            hb[tt] += 1024;
        }

        f32x4 acc[2][8];
#pragma unroll
        for (int tt = 0; tt < 2; ++tt)
#pragma unroll
            for (int nb = 0; nb < 8; ++nb) {
                f32x4 a;
                a[0] = bias8[nb]; a[1] = bias8[nb]; a[2] = bias8[nb]; a[3] = bias8[nb];
                acc[tt][nb] = __builtin_amdgcn_mfma_f32_16x16x32_f16(a_f[tt], WA[nb], a, 0, 0, 0);
            }
#pragma unroll
        for (int tt = 0; tt < 2; ++tt)
#pragma unroll
            for (int nb = 0; nb < 8; ++nb)
                acc[tt][nb] = __builtin_amdgcn_mfma_f32_16x16x32_f16(a_b[tt], WB[nb], acc[tt][nb], 0, 0, 0);
#pragma unroll
        for (int tt = 0; tt < 2; ++tt)
#pragma unroll
            for (int nb = 0; nb < 8; ++nb)
                acc[tt][nb] = __builtin_amdgcn_mfma_f32_16x16x32_f16(h1frag[tt], WH[nb], acc[tt][nb], 0, 0, 0);

#pragma unroll
        for (int tt = 0; tt < 2; ++tt) {
            _Float16* T = tt ? T1 : T0;
#pragma unroll
            for (int r = 0; r < 4; ++r) {
                f16x2 pk;
#pragma unroll
                for (int p = 0; p < 2; ++p) {
                    float h = cell3(acc[tt][0 + p][r], acc[tt][2 + p][r],
                                    acc[tt][4 + p][r], acc[tt][6 + p][r], c1[tt][r][p]);
                    h1f[tt][r][p] = h;
                    pk[p] = (_Float16)h;
                }
                *(f16x2*)(T + (quad * 4 + r) * 40 + 2 * n0) = pk;
            }
        }
#pragma unroll
        for (int tt = 0; tt < 2; ++tt)
            h1frag[tt] = *(const f16x8*)((tt ? T1 : T0) + n0 * 40 + quad * 8);
    }
    // a_f/a_b still hold t=14 (input to the 1-step L1 backward).

    // ---- L1 backward, single step from zero state (f-gate dead: c=0) ----
    // Properly-sized register staging: accb[tt][q], q = gate-pair index
    // (q=0,1 -> i with p=q&1; q=2,3 -> g; q=4,5 -> o).
    float h1b[2][4][2];
    {
        const float* Wb = Wih + 128 * 64;   // dir 1
        const float* bb = bs + 128;
        const int gsel[3] = {0, 2, 3};      // gate blocks i, g, o in 4H layout
        f32x4 accb[2][6];
#pragma unroll
        for (int q = 0; q < 6; ++q) {
            const int row = gsel[q >> 1] * 32 + 2 * n0 + (q & 1);
            const f16x8 wa = bfrag8(Wb + row * 64 + quad * 8);
            const f16x8 wb = bfrag8(Wb + row * 64 + 32 + quad * 8);
            const float bv = bb[row];
#pragma unroll
            for (int tt = 0; tt < 2; ++tt) {
                f32x4 a;
                a[0] = bv; a[1] = bv; a[2] = bv; a[3] = bv;
                a = __builtin_amdgcn_mfma_f32_16x16x32_f16(a_f[tt], wa, a, 0, 0, 0);
                a = __builtin_amdgcn_mfma_f32_16x16x32_f16(a_b[tt], wb, a, 0, 0, 0);
                accb[tt][q] = a;
            }
        }
#pragma unroll
        for (int tt = 0; tt < 2; ++tt)
#pragma unroll
            for (int r = 0; r < 4; ++r)
#pragma unroll
                for (int p = 0; p < 2; ++p) {
                    const float i_ = accb[tt][0 + p][r];
                    const float g_ = accb[tt][2 + p][r];
                    const float o_ = accb[tt][4 + p][r];
                    float Bv = 1.0f + __builtin_amdgcn_exp2f(-LOG2E * i_);
                    float Cv = 1.0f + __builtin_amdgcn_exp2f(LOG2E2 * g_);
                    float cv = (Cv - 2.0f) * __builtin_amdgcn_rcpf(Bv * Cv);
                    float D  = 1.0f + __builtin_amdgcn_exp2f(-LOG2E * o_);
                    float E  = 1.0f + __builtin_amdgcn_exp2f(LOG2E2 * cv);
                    h1b[tt][r][p] = (E - 2.0f) * __builtin_amdgcn_rcpf(D * E);
                }
    }

    // ---- FC + masks + atomic combine (perm: lane n0 owns j = 2n0, 2n0+1) ----
#pragma unroll
    for (int tt = 0; tt < 2; ++tt) {
        const int sbase = chunk_base + (tpair + tt) * 16;
        const int half  = sbase >> 15;                 // wave-uniform per tile

        float wf[2][2], wk[2][2];
#pragma unroll
        for (int o = 0; o < 2; ++o)
#pragma unroll
            for (int p = 0; p < 2; ++p) {
                if (m == 0) {
                    wf[o][p] = lvl_fc_W[o * 64 + 2 * n0 + p];
                    wk[o][p] = lvl_fc_W[o * 64 + 32 + 2 * n0 + p];
                } else {
                    wf[o][p] = vor_fc_W[o * 128 + half * 64 + 2 * n0 + p];
                    wk[o][p] = vor_fc_W[o * 128 + half * 64 + 32 + 2 * n0 + p];
                }
            }
        float pr[4][2];
#pragma unroll
        for (int r = 0; r < 4; ++r)
#pragma unroll
            for (int o = 0; o < 2; ++o)
                pr[r][o] = wf[o][0] * h1f[tt][r][0] + wf[o][1] * h1f[tt][r][1]
                         + wk[o][0] * h1b[tt][r][0] + wk[o][1] * h1b[tt][r][1];
#pragma unroll
        for (int mask = 1; mask < 16; mask <<= 1)
#pragma unroll
            for (int r = 0; r < 4; ++r)
#pragma unroll
                for (int o = 0; o < 2; ++o)
                    pr[r][o] += __shfl_xor(pr[r][o], mask);

        if (n0 < 4) {
            const int r  = n0;
            const int sb = sbase + quad * 4 + r;
            const int b  = sb & 32767;
            const float* dp = dir_input + (size_t)b * 6;
            float mx = dp[0];
            int dmax = 0;
#pragma unroll
            for (int i = 1; i < 6; ++i) {
                const float v = dp[i];
                if (v > mx) { mx = v; dmax = i; }
            }
            float mask, b0v, b1v;
            if (m == 0) {
                mask = (half == 0) ? ((dmax == 2 || dmax == 3) ? 1.0f : 0.0f)
                                   : ((dmax == 0 || dmax == 5) ? 1.0f : 0.0f);
                b0v = lvl_fc_b[0]; b1v = lvl_fc_b[1];
            } else {
                mask = (dmax == 1 || dmax == 4) ? 1.0f : 0.0f;
                b0v = (half == 0) ? vor_fc_b[0] : 0.0f;
                b1v = (half == 0) ? vor_fc_b[1] : 0.0f;
            }
            atomicAdd(out + (size_t)b * 2 + 0, (pr[r][0] + b0v) * mask);
            atomicAdd(out + (size_t)b * 2 + 1, (pr[r][1] + b1v) * mask);
        }
    }
}

extern "C" void kernel_launch(void* const* d_in, const int* in_sizes, int n_in,
                              void* d_out, int out_size, void* d_ws, size_t ws_size,
                              hipStream_t stream) {
    const float* dir_input = (const float*)d_in[0];
    const float* pos       = (const float*)d_in[1];
    const float* lvl_Wih0  = (const float*)d_in[2];
    const float* lvl_Whh0  = (const float*)d_in[3];
    const float* lvl_b0    = (const float*)d_in[4];
    const float* lvl_Wih1  = (const float*)d_in[5];
    const float* lvl_Whh1  = (const float*)d_in[6];
    const float* lvl_b1    = (const float*)d_in[7];
    const float* vor_Wih0  = (const float*)d_in[8];
    const float* vor_Whh0  = (const float*)d_in[9];
    const float* vor_b0    = (const float*)d_in[10];
    const float* vor_Wih1  = (const float*)d_in[11];
    const float* vor_Whh1  = (const float*)d_in[12];
    const float* vor_b1    = (const float*)d_in[13];
    const float* lvl_fc_W  = (const float*)d_in[14];
    const float* lvl_fc_b  = (const float*)d_in[15];
    const float* vor_fc_W  = (const float*)d_in[16];
    const float* vor_fc_b  = (const float*)d_in[17];
    float* out = (float*)d_out;
    _Float16* hist = (_Float16*)d_ws;

    (void)in_sizes; (void)n_in;

    hipMemsetAsync(d_out, 0, (size_t)out_size * sizeof(float), stream);

    // per sample: 2 models * 15 t * 64 k * 2 B = 3840 B of history
    int S_C = 32768;                                   // 126 MB chunk (L3-resident)
    while ((size_t)S_C * 3840ull > ws_size && S_C > 128) S_C >>= 1;

    for (int base = 0; base < 65536; base += S_C) {
        const int NT = S_C / 16;
        dim3 blk(256, 1, 1);
        dim3 g1(NT / 8, 4, 1);
        hipLaunchKernelGGL(k1_l0, g1, blk, 0, stream,
                           pos, lvl_Wih0, lvl_Whh0, lvl_b0,
                           vor_Wih0, vor_Whh0, vor_b0,
                           hist, base, NT);
        dim3 g2(NT / 8, 2, 1);
        hipLaunchKernelGGL(k2_l1, g2, blk, 0, stream,
                           dir_input, lvl_Wih1, lvl_Whh1, lvl_b1,
                           vor_Wih1, vor_Whh1, vor_b1,
                           lvl_fc_W, lvl_fc_b, vor_fc_W, vor_fc_b,
                           hist, out, base, NT);
    }
}

// Round 8
// 363.487 us; speedup vs baseline: 1.0561x; 1.0561x over previous
//
#include <hip/hip_runtime.h>
#include <hip/hip_bf16.h>

typedef _Float16 f16x8 __attribute__((ext_vector_type(8)));
typedef _Float16 f16x4 __attribute__((ext_vector_type(4)));
typedef float    f32x4 __attribute__((ext_vector_type(4)));

#define LOG2E  1.44269504f
#define LOG2E2 2.88539008f

// Gates arrive PRE-SCALED (scale folded into weights/bias):
//   i~ = -log2e * i, f~ = -log2e * f, g~ = 2log2e * g, o~ = -log2e * o
// sigm(f) = 1/(1+2^f~);  tanh(g) = (2^g~ - 1)/(2^g~ + 1)
// c' = (c*B*C + A*(eg-1)) * rcp(A*B*C);  h = (ec-1)*rcp((1+eo)*(1+ec))
__device__ __forceinline__ float cellT(float fi, float ff, float fg, float fo, float& c) {
    float ei = __builtin_amdgcn_exp2f(fi);
    float ef = __builtin_amdgcn_exp2f(ff);
    float eg = __builtin_amdgcn_exp2f(fg);
    float A  = 1.0f + ef;
    float B  = 1.0f + ei;
    float C  = 1.0f + eg;
    float Cm2 = eg - 1.0f;
    float BC = B * C;
    float cn = fmaf(c, BC, A * Cm2) * __builtin_amdgcn_rcpf(A * BC);
    c = cn;
    float eo = __builtin_amdgcn_exp2f(fo);
    float ec = __builtin_amdgcn_exp2f(LOG2E2 * cn);
    return (ec - 1.0f) * __builtin_amdgcn_rcpf((1.0f + eo) * (1.0f + ec));
}

// Load 8 fp32, scale, convert to f16x8 (A-frag chunk).
__device__ __forceinline__ f16x8 afrag8(const float* __restrict__ p, float s) {
    const float4 w0 = *(const float4*)p;
    const float4 w1 = *(const float4*)(p + 4);
    f16x8 v;
    v[0] = (_Float16)(w0.x * s); v[1] = (_Float16)(w0.y * s);
    v[2] = (_Float16)(w0.z * s); v[3] = (_Float16)(w0.w * s);
    v[4] = (_Float16)(w1.x * s); v[5] = (_Float16)(w1.y * s);
    v[6] = (_Float16)(w1.z * s); v[7] = (_Float16)(w1.w * s);
    return v;
}

// gate scale for A-slice nb (rows J = nb*16..+15; gate = nb>>1)
__device__ __forceinline__ float gscale(int nb) {
    return ((nb >> 1) == 2) ? LOG2E2 : -LOG2E;
}

#define HAVE_K16 __has_builtin(__builtin_amdgcn_mfma_f32_16x16x16f16)

// ---------------------------------------------------------------------------
// K1: layer-0 scans, transposed-gates. 1 wave = 1 tile = 16 samples.
// A = weight rows (A[m=J_local via lane n0][k]); B = h^T (B[k][n=sample n0]);
// D[row = J_local = quad*4+r][col = sample = n0]. Bias folded into K (k=4).
// grid = (NT/4, 4[model*2+dir]).
// hist: hist[(m*NT+tile)*15*1024 + t*1024 + dir*512 + lane*8] (f16x8 B-frags).
// ---------------------------------------------------------------------------
__global__ __launch_bounds__(256, 4) void k1_l0(
    const float* __restrict__ pos,            // [32768,30,4]
    const float* __restrict__ lvl_Wih0, const float* __restrict__ lvl_Whh0,
    const float* __restrict__ lvl_b0,
    const float* __restrict__ vor_Wih0, const float* __restrict__ vor_Whh0,
    const float* __restrict__ vor_b0,
    _Float16* __restrict__ hist, int chunk_base, int NT)
{
    const int lane = threadIdx.x & 63;
    const int wv   = threadIdx.x >> 6;
    const int n0   = lane & 15;
    const int quad = lane >> 4;
    const int tile = blockIdx.x * 4 + wv;
    const int m    = blockIdx.y >> 1;
    const int dir  = blockIdx.y & 1;

    const float* Wih = (m ? vor_Wih0 : lvl_Wih0) + dir * 128 * 4;   // [128][4]
    const float* Whh = (m ? vor_Whh0 : lvl_Whh0) + dir * 128 * 32;  // [128][32]
    const float* bs  = (m ? vor_b0   : lvl_b0)   + dir * 128;       // [128]

    f16x8 WhhA[8];
#if HAVE_K16
    f16x4 WihA[8];
#else
    f16x8 WihA[8];
#endif
#pragma unroll
    for (int nb = 0; nb < 8; ++nb) {
        const int J = nb * 16 + n0;           // A-frag row (m = n0)
        const float s = gscale(nb);
        WhhA[nb] = afrag8(Whh + J * 32 + quad * 8, s);
#if HAVE_K16
        f16x4 v = {(_Float16)0.0f, (_Float16)0.0f, (_Float16)0.0f, (_Float16)0.0f};
        if (quad == 0) {
            const float4 w = *(const float4*)(Wih + J * 4);
            v[0] = (_Float16)(w.x * s); v[1] = (_Float16)(w.y * s);
            v[2] = (_Float16)(w.z * s); v[3] = (_Float16)(w.w * s);
        } else if (quad == 1) {
            v[0] = (_Float16)(bs[J] * s);     // k=4 bias slot
        }
        WihA[nb] = v;
#else
        f16x8 v;
#pragma unroll
        for (int r = 0; r < 8; ++r) v[r] = (_Float16)0.0f;
        if (quad == 0) {
            const float4 w = *(const float4*)(Wih + J * 4);
            v[0] = (_Float16)(w.x * s); v[1] = (_Float16)(w.y * s);
            v[2] = (_Float16)(w.z * s); v[3] = (_Float16)(w.w * s);
            v[4] = (_Float16)(bs[J] * s);
        }
        WihA[nb] = v;
#endif
    }

    // LDS transpose buffer: per wave, 16 samples x 48-elem (96 B) stride
    __shared__ _Float16 tb[4][768];
    _Float16* T = tb[wv];

    const int s0   = chunk_base + tile * 16 + n0;
    const int b    = s0 & 32767;
    const int hf   = s0 >> 15;
    const float* xp = pos + ((size_t)b * 30 + hf * 15 + (dir ? 14 : 0)) * 4;
    const int xstep = dir ? -4 : 4;

    _Float16* hp = hist + ((size_t)(m * NT + tile)) * 15 * 1024
                 + (size_t)(dir ? 14 : 0) * 1024 + dir * 512 + lane * 8;
    const int hstep = dir ? -1024 : 1024;

    float c[4][2];
#pragma unroll
    for (int r = 0; r < 4; ++r) { c[r][0] = 0.0f; c[r][1] = 0.0f; }

    f16x8 hB;                                  // h^T B-frag: lane n0 holds k=q*8+j
#pragma unroll
    for (int r = 0; r < 8; ++r) hB[r] = (_Float16)0.0f;

    const f32x4 z4 = {0.0f, 0.0f, 0.0f, 0.0f};

#pragma unroll 1
    for (int ti = 0; ti < 15; ++ti) {
        const float4 xv = *(const float4*)xp;
        xp += xstep;
#if HAVE_K16
        f16x4 xB = {(_Float16)0.0f, (_Float16)0.0f, (_Float16)0.0f, (_Float16)0.0f};
        if (quad == 0) {
            xB[0] = (_Float16)xv.x; xB[1] = (_Float16)xv.y;
            xB[2] = (_Float16)xv.z; xB[3] = (_Float16)xv.w;
        } else if (quad == 1) {
            xB[0] = (_Float16)1.0f;
        }
#else
        f16x8 xB;
#pragma unroll
        for (int r = 0; r < 8; ++r) xB[r] = (_Float16)0.0f;
        if (quad == 0) {
            xB[0] = (_Float16)xv.x; xB[1] = (_Float16)xv.y;
            xB[2] = (_Float16)xv.z; xB[3] = (_Float16)xv.w;
            xB[4] = (_Float16)1.0f;
        }
#endif

        f32x4 acc[8];
#pragma unroll
        for (int nb = 0; nb < 8; ++nb)
#if HAVE_K16
            acc[nb] = __builtin_amdgcn_mfma_f32_16x16x16f16(WihA[nb], xB, z4, 0, 0, 0);
#else
            acc[nb] = __builtin_amdgcn_mfma_f32_16x16x32_f16(WihA[nb], xB, z4, 0, 0, 0);
#endif
#pragma unroll
        for (int nb = 0; nb < 8; ++nb)
            acc[nb] = __builtin_amdgcn_mfma_f32_16x16x32_f16(WhhA[nb], hB, acc[nb], 0, 0, 0);

        // lane owns cells j = quad*4+r (even nb) and 16+quad*4+r (odd nb) of sample n0
        f16x4 lo, hi;
#pragma unroll
        for (int r = 0; r < 4; ++r) {
            lo[r] = (_Float16)cellT(acc[0][r], acc[2][r], acc[4][r], acc[6][r], c[r][0]);
            hi[r] = (_Float16)cellT(acc[1][r], acc[3][r], acc[5][r], acc[7][r], c[r][1]);
        }
        *(f16x4*)(T + n0 * 48 + 4 * quad) = lo;          // j = 4q..4q+3
        *(f16x4*)(T + n0 * 48 + 16 + 4 * quad) = hi;     // j = 16+4q..+3
        hB = *(const f16x8*)(T + n0 * 48 + 8 * quad);    // j = 8q..8q+7

        *(f16x8*)hp = hB;
        hp += hstep;
    }
}

// ---------------------------------------------------------------------------
// K2: layer-1 fwd scan + 1-step bwd + FC epilogue, transposed-gates.
// 1 wave = 2 tiles. grid = (NT/8, 2[model]).
// BIAS C-INIT USES C/D ROW CONVENTION: row = nb*16 + quad*4 + r  (R7 bug fix).
// ---------------------------------------------------------------------------
__global__ __launch_bounds__(256, 2) void k2_l1(
    const float* __restrict__ dir_input,      // [32768,6]
    const float* __restrict__ lvl_Wih1, const float* __restrict__ lvl_Whh1,
    const float* __restrict__ lvl_b1,
    const float* __restrict__ vor_Wih1, const float* __restrict__ vor_Whh1,
    const float* __restrict__ vor_b1,
    const float* __restrict__ lvl_fc_W, const float* __restrict__ lvl_fc_b,
    const float* __restrict__ vor_fc_W, const float* __restrict__ vor_fc_b,
    const _Float16* __restrict__ hist, float* __restrict__ out,
    int chunk_base, int NT)
{
    const int lane  = threadIdx.x & 63;
    const int wv    = threadIdx.x >> 6;
    const int n0    = lane & 15;
    const int quad  = lane >> 4;
    const int tpair = (blockIdx.x * 4 + wv) * 2;
    const int m     = blockIdx.y;

    const float* Wih = m ? vor_Wih1 : lvl_Wih1;   // [2][128][64]
    const float* Whh = m ? vor_Whh1 : lvl_Whh1;   // [2][128][32]
    const float* bs  = m ? vor_b1   : lvl_b1;     // [2][128]

    f16x8 WA[8], WB[8], WH[8];
    f32x4 biasv[8];                               // C/D-row-indexed scaled bias
#pragma unroll
    for (int nb = 0; nb < 8; ++nb) {
        const int J = nb * 16 + n0;               // A-frag row (m = n0)
        const float s = gscale(nb);
        WA[nb] = afrag8(Wih + J * 64 + quad * 8, s);
        WB[nb] = afrag8(Wih + J * 64 + 32 + quad * 8, s);
        WH[nb] = afrag8(Whh + J * 32 + quad * 8, s);
        const float4 bq = *(const float4*)(bs + nb * 16 + quad * 4);   // C/D rows
        f32x4 bv; bv[0] = bq.x * s; bv[1] = bq.y * s; bv[2] = bq.z * s; bv[3] = bq.w * s;
        biasv[nb] = bv;
    }

    __shared__ _Float16 tb[4][2][768];

    const _Float16* hb[2];
#pragma unroll
    for (int tt = 0; tt < 2; ++tt)
        hb[tt] = hist + ((size_t)(m * NT + tpair + tt)) * 15 * 1024 + lane * 8;

    float c1[2][4][2];
#pragma unroll
    for (int tt = 0; tt < 2; ++tt)
#pragma unroll
        for (int r = 0; r < 4; ++r) { c1[tt][r][0] = 0.0f; c1[tt][r][1] = 0.0f; }
    f16x8 h1B[2];
#pragma unroll
    for (int tt = 0; tt < 2; ++tt)
#pragma unroll
        for (int r = 0; r < 8; ++r) h1B[tt][r] = (_Float16)0.0f;
    float h1f_a[2][4], h1f_b[2][4];
    f16x8 a_f[2], a_b[2];

#pragma unroll 1
    for (int t = 0; t < 15; ++t) {
#pragma unroll
        for (int tt = 0; tt < 2; ++tt) {
            a_f[tt] = *(const f16x8*)hb[tt];
            a_b[tt] = *(const f16x8*)(hb[tt] + 512);
            hb[tt] += 1024;
        }

        f32x4 acc[2][8];
#pragma unroll
        for (int tt = 0; tt < 2; ++tt)
#pragma unroll
            for (int nb = 0; nb < 8; ++nb)
                acc[tt][nb] = __builtin_amdgcn_mfma_f32_16x16x32_f16(WA[nb], a_f[tt], biasv[nb], 0, 0, 0);
#pragma unroll
        for (int tt = 0; tt < 2; ++tt)
#pragma unroll
            for (int nb = 0; nb < 8; ++nb)
                acc[tt][nb] = __builtin_amdgcn_mfma_f32_16x16x32_f16(WB[nb], a_b[tt], acc[tt][nb], 0, 0, 0);
#pragma unroll
        for (int tt = 0; tt < 2; ++tt)
#pragma unroll
            for (int nb = 0; nb < 8; ++nb)
                acc[tt][nb] = __builtin_amdgcn_mfma_f32_16x16x32_f16(WH[nb], h1B[tt], acc[tt][nb], 0, 0, 0);

#pragma unroll
        for (int tt = 0; tt < 2; ++tt) {
            _Float16* T = tb[wv][tt];
            f16x4 lo, hi;
#pragma unroll
            for (int r = 0; r < 4; ++r) {
                float ha  = cellT(acc[tt][0][r], acc[tt][2][r], acc[tt][4][r], acc[tt][6][r], c1[tt][r][0]);
                float hbv = cellT(acc[tt][1][r], acc[tt][3][r], acc[tt][5][r], acc[tt][7][r], c1[tt][r][1]);
                h1f_a[tt][r] = ha; h1f_b[tt][r] = hbv;
                lo[r] = (_Float16)ha; hi[r] = (_Float16)hbv;
            }
            *(f16x4*)(T + n0 * 48 + 4 * quad) = lo;
            *(f16x4*)(T + n0 * 48 + 16 + 4 * quad) = hi;
            h1B[tt] = *(const f16x8*)(T + n0 * 48 + 8 * quad);
        }
    }
    // a_f/a_b hold t=14 (input to the 1-step L1 backward).

    // ---- L1 backward, single step from zero state (f-gate dead) ----
    float h1b_a[2][4], h1b_b[2][4];
    {
        const float* Wb = Wih + 128 * 64;   // dir 1
        const float* bb = bs + 128;
        const int nbs[6] = {0, 1, 4, 5, 6, 7};   // i, g, o slices
        f32x4 accb[2][6];
#pragma unroll
        for (int q = 0; q < 6; ++q) {
            const int nb = nbs[q];
            const int J = nb * 16 + n0;
            const float s = gscale(nb);
            const f16x8 wa = afrag8(Wb + J * 64 + quad * 8, s);
            const f16x8 wb = afrag8(Wb + J * 64 + 32 + quad * 8, s);
            const float4 bq = *(const float4*)(bb + nb * 16 + quad * 4);   // C/D rows
            f32x4 bv; bv[0] = bq.x * s; bv[1] = bq.y * s; bv[2] = bq.z * s; bv[3] = bq.w * s;
#pragma unroll
            for (int tt = 0; tt < 2; ++tt) {
                f32x4 a = __builtin_amdgcn_mfma_f32_16x16x32_f16(wa, a_f[tt], bv, 0, 0, 0);
                a = __builtin_amdgcn_mfma_f32_16x16x32_f16(wb, a_b[tt], a, 0, 0, 0);
                accb[tt][q] = a;
            }
        }
#pragma unroll
        for (int tt = 0; tt < 2; ++tt)
#pragma unroll
            for (int r = 0; r < 4; ++r) {
#pragma unroll
                for (int p = 0; p < 2; ++p) {
                    const float i_ = accb[tt][0 + p][r];   // scaled: -log2e * i
                    const float g_ = accb[tt][2 + p][r];   // scaled: 2log2e * g
                    const float o_ = accb[tt][4 + p][r];   // scaled: -log2e * o
                    float ei = __builtin_amdgcn_exp2f(i_);
                    float eg = __builtin_amdgcn_exp2f(g_);
                    float Bv = 1.0f + ei;
                    float C  = 1.0f + eg;
                    float cv = (eg - 1.0f) * __builtin_amdgcn_rcpf(Bv * C);
                    float eo = __builtin_amdgcn_exp2f(o_);
                    float ec = __builtin_amdgcn_exp2f(LOG2E2 * cv);
                    float h = (ec - 1.0f) * __builtin_amdgcn_rcpf((1.0f + eo) * (1.0f + ec));
                    if (p == 0) h1b_a[tt][r] = h; else h1b_b[tt][r] = h;
                }
            }
    }

    // ---- FC + masks + atomic combine. Lane owns j = quad*4+r (+16) of sample n0.
#pragma unroll
    for (int tt = 0; tt < 2; ++tt) {
        const int sbase = chunk_base + (tpair + tt) * 16;
        const int half  = sbase >> 15;                 // wave-uniform per tile

        float pr[2];
#pragma unroll
        for (int o = 0; o < 2; ++o) {
            const float* Wr = (m == 0) ? (lvl_fc_W + o * 64)
                                       : (vor_fc_W + o * 128 + half * 64);
            const float4 wfa = *(const float4*)(Wr + quad * 4);        // h1f j=q*4+r
            const float4 wfb = *(const float4*)(Wr + 16 + quad * 4);   // h1f j=16+...
            const float4 wba = *(const float4*)(Wr + 32 + quad * 4);   // h1b j=q*4+r
            const float4 wbb = *(const float4*)(Wr + 48 + quad * 4);   // h1b j=16+...
            float a = wfa.x * h1f_a[tt][0] + wfa.y * h1f_a[tt][1]
                    + wfa.z * h1f_a[tt][2] + wfa.w * h1f_a[tt][3];
            a += wfb.x * h1f_b[tt][0] + wfb.y * h1f_b[tt][1]
               + wfb.z * h1f_b[tt][2] + wfb.w * h1f_b[tt][3];
            a += wba.x * h1b_a[tt][0] + wba.y * h1b_a[tt][1]
               + wba.z * h1b_a[tt][2] + wba.w * h1b_a[tt][3];
            a += wbb.x * h1b_b[tt][0] + wbb.y * h1b_b[tt][1]
               + wbb.z * h1b_b[tt][2] + wbb.w * h1b_b[tt][3];
            pr[o] = a;
        }
        // reduce over quads (lane bits 4,5)
#pragma unroll
        for (int o = 0; o < 2; ++o) {
            pr[o] += __shfl_xor(pr[o], 16);
            pr[o] += __shfl_xor(pr[o], 32);
        }

        if (quad == 0) {
            const int sb = sbase + n0;
            const int b  = sb & 32767;
            const float* dp = dir_input + (size_t)b * 6;
            float mx = dp[0];
            int dmax = 0;
#pragma unroll
            for (int i = 1; i < 6; ++i) {
                const float v = dp[i];
                if (v > mx) { mx = v; dmax = i; }
            }
            float mask, b0v, b1v;
            if (m == 0) {
                mask = (half == 0) ? ((dmax == 2 || dmax == 3) ? 1.0f : 0.0f)
                                   : ((dmax == 0 || dmax == 5) ? 1.0f : 0.0f);
                b0v = lvl_fc_b[0]; b1v = lvl_fc_b[1];
            } else {
                mask = (dmax == 1 || dmax == 4) ? 1.0f : 0.0f;
                b0v = (half == 0) ? vor_fc_b[0] : 0.0f;
                b1v = (half == 0) ? vor_fc_b[1] : 0.0f;
            }
            atomicAdd(out + (size_t)b * 2 + 0, (pr[0] + b0v) * mask);
            atomicAdd(out + (size_t)b * 2 + 1, (pr[1] + b1v) * mask);
        }
    }
}

extern "C" void kernel_launch(void* const* d_in, const int* in_sizes, int n_in,
                              void* d_out, int out_size, void* d_ws, size_t ws_size,
                              hipStream_t stream) {
    const float* dir_input = (const float*)d_in[0];
    const float* pos       = (const float*)d_in[1];
    const float* lvl_Wih0  = (const float*)d_in[2];
    const float* lvl_Whh0  = (const float*)d_in[3];
    const float* lvl_b0    = (const float*)d_in[4];
    const float* lvl_Wih1  = (const float*)d_in[5];
    const float* lvl_Whh1  = (const float*)d_in[6];
    const float* lvl_b1    = (const float*)d_in[7];
    const float* vor_Wih0  = (const float*)d_in[8];
    const float* vor_Whh0  = (const float*)d_in[9];
    const float* vor_b0    = (const float*)d_in[10];
    const float* vor_Wih1  = (const float*)d_in[11];
    const float* vor_Whh1  = (const float*)d_in[12];
    const float* vor_b1    = (const float*)d_in[13];
    const float* lvl_fc_W  = (const float*)d_in[14];
    const float* lvl_fc_b  = (const float*)d_in[15];
    const float* vor_fc_W  = (const float*)d_in[16];
    const float* vor_fc_b  = (const float*)d_in[17];
    float* out = (float*)d_out;
    _Float16* hist = (_Float16*)d_ws;

    (void)in_sizes; (void)n_in;

    hipMemsetAsync(d_out, 0, (size_t)out_size * sizeof(float), stream);

    // per sample: 2 models * 15 t * 64 k * 2 B = 3840 B of history
    int S_C = 32768;                                   // 126 MB chunk (L3-resident)
    while ((size_t)S_C * 3840ull > ws_size && S_C > 128) S_C >>= 1;

    for (int base = 0; base < 65536; base += S_C) {
        const int NT = S_C / 16;
        dim3 blk(256, 1, 1);
        dim3 g1(NT / 4, 4, 1);
        hipLaunchKernelGGL(k1_l0, g1, blk, 0, stream,
                           pos, lvl_Wih0, lvl_Whh0, lvl_b0,
                           vor_Wih0, vor_Whh0, vor_b0,
                           hist, base, NT);
        dim3 g2(NT / 8, 2, 1);
        hipLaunchKernelGGL(k2_l1, g2, blk, 0, stream,
                           dir_input, lvl_Wih1, lvl_Whh1, lvl_b1,
                           vor_Wih1, vor_Whh1, vor_b1,
                           lvl_fc_W, lvl_fc_b, vor_fc_W, vor_fc_b,
                           hist, out, base, NT);
    }
}